// Round 1
// baseline (405.146 us; speedup 1.0000x reference)
//
#include <hip/hip_runtime.h>
#include <hip/hip_bf16.h>

// Problem dims (fixed by reference setup)
#define B_   16
#define N_   8
#define C_   512
#define D_   768
#define HH   64
#define WW   64
#define HW   4096          // 64*64 pixels per batch

typedef __bf16 bf16;
typedef __attribute__((ext_vector_type(8))) __bf16 bf16x8;
typedef __attribute__((ext_vector_type(4))) __bf16 bf16x4;
typedef __attribute__((ext_vector_type(4))) float  f32x4;

// ---------------------------------------------------------------------------
// K1a: Q[b,n,c] = sum_d (se[b,n,d]*weights[n]) * wq_w[c,d] + wq_b[c]
// grid 128=(b,n), block 512=c
__global__ __launch_bounds__(512) void k_q(const float* __restrict__ se,
                                           const float* __restrict__ weights,
                                           const float* __restrict__ wq_w,
                                           const float* __restrict__ wq_b,
                                           float* __restrict__ Q) {
    int bn = blockIdx.x;
    int n  = bn & 7;
    float wt = weights[n];                       // uniform
    const float* we = se + (size_t)bn * D_;      // uniform base
    int c = threadIdx.x;
    const f32x4* wr = (const f32x4*)(wq_w + (size_t)c * D_);
    float acc = wq_b[c];
    #pragma unroll 4
    for (int i = 0; i < D_ / 4; ++i) {
        f32x4 w4 = wr[i];
        acc += (we[4*i+0] * wt) * w4[0];
        acc += (we[4*i+1] * wt) * w4[1];
        acc += (we[4*i+2] * wt) * w4[2];
        acc += (we[4*i+3] * wt) * w4[3];
    }
    Q[(size_t)bn * C_ + c] = acc;
}

// ---------------------------------------------------------------------------
// K1b: Qk[b,n,m] = sum_o Q[b,n,o] * wk_w[o,m]   (wk_b cancels in softmax)
// grid 128=(b,n), block 128 (each thread = 4 consecutive m)
__global__ __launch_bounds__(128) void k_qk(const float* __restrict__ Q,
                                            const float* __restrict__ wk_w,
                                            float* __restrict__ Qk) {
    int bn = blockIdx.x;
    const float* q = Q + (size_t)bn * C_;        // uniform base
    int t = threadIdx.x;                          // m-quad
    f32x4 acc = {0.f, 0.f, 0.f, 0.f};
    const f32x4* wk4 = (const f32x4*)wk_w;
    #pragma unroll 4
    for (int o = 0; o < C_; ++o) {
        float qo = q[o];                          // uniform -> scalar load
        f32x4 w = wk4[(size_t)o * (C_ / 4) + t];
        acc[0] += qo * w[0]; acc[1] += qo * w[1];
        acc[2] += qo * w[2]; acc[3] += qo * w[3];
    }
    ((f32x4*)Qk)[(size_t)bn * (C_ / 4) + t] = acc;
}

// ---------------------------------------------------------------------------
// K1c: W2[o,c] = sum_m wo_w[o,m]*wv_w[m,c]  (bf16 out);  b2[o] = wo_w[o,:]·wv_b
// grid 128 (4 o-rows each), block 128 (each thread = 4 consecutive c)
__global__ __launch_bounds__(128) void k_w2(const float* __restrict__ wo_w,
                                            const float* __restrict__ wv_w,
                                            const float* __restrict__ wv_b,
                                            bf16* __restrict__ W2,
                                            float* __restrict__ b2) {
    int o0 = blockIdx.x * 4;
    int t  = threadIdx.x;                         // c-quad
    const float* r0 = wo_w + (size_t)o0 * C_;     // uniform rows
    f32x4 a0 = {0,0,0,0}, a1 = {0,0,0,0}, a2 = {0,0,0,0}, a3 = {0,0,0,0};
    const f32x4* wv4 = (const f32x4*)wv_w;
    #pragma unroll 2
    for (int m = 0; m < C_; ++m) {
        f32x4 v = wv4[(size_t)m * (C_ / 4) + t];
        float w0 = r0[m], w1 = r0[C_ + m], w2 = r0[2 * C_ + m], w3 = r0[3 * C_ + m];
        a0[0]+=w0*v[0]; a0[1]+=w0*v[1]; a0[2]+=w0*v[2]; a0[3]+=w0*v[3];
        a1[0]+=w1*v[0]; a1[1]+=w1*v[1]; a1[2]+=w1*v[2]; a1[3]+=w1*v[3];
        a2[0]+=w2*v[0]; a2[1]+=w2*v[1]; a2[2]+=w2*v[2]; a2[3]+=w2*v[3];
        a3[0]+=w3*v[0]; a3[1]+=w3*v[1]; a3[2]+=w3*v[2]; a3[3]+=w3*v[3];
    }
    f32x4 accs[4] = {a0, a1, a2, a3};
    #pragma unroll
    for (int j = 0; j < 4; ++j) {
        bf16x4 hv;
        hv[0] = (bf16)accs[j][0]; hv[1] = (bf16)accs[j][1];
        hv[2] = (bf16)accs[j][2]; hv[3] = (bf16)accs[j][3];
        *(bf16x4*)(W2 + (size_t)(o0 + j) * C_ + t * 4) = hv;
    }
    if (t < 4) {
        float sb = 0.f;
        const float* rr = wo_w + (size_t)(o0 + t) * C_;
        for (int m = 0; m < C_; ++m) sb += rr[m] * wv_b[m];
        b2[o0 + t] = sb;
    }
}

// ---------------------------------------------------------------------------
// K2: per (b,h): scores t[n,w] = Qk[b,n,:]·x[b,:,h,w]/sqrt(768); softmax over w;
//     s[b,p] = sum_n attn.  Also writes xT[b,p,c] = bf16(x[b,c,p]) (transpose).
// grid 1024=(b,h), block 512 (wave = n, lane = w)
__global__ __launch_bounds__(512) void k_scores(const float* __restrict__ x,
                                                const float* __restrict__ Qk,
                                                float* __restrict__ s,
                                                bf16* __restrict__ xT) {
    int blk = blockIdx.x;
    int b = blk >> 6, h = blk & 63;
    int tid = threadIdx.x;
    int n = tid >> 6, w = tid & 63;
    __shared__ float attn_lds[N_][WW];

    // ---- phase 1: scores + softmax ----
    int n_u = __builtin_amdgcn_readfirstlane(n);  // wave-uniform
    const float* qrow = Qk + ((size_t)(b * N_ + n_u)) * C_;
    const float* xcol = x + (size_t)b * C_ * HW + h * WW + w;
    float t = 0.f;
    #pragma unroll 8
    for (int c = 0; c < C_; ++c)
        t = fmaf(qrow[c], xcol[(size_t)c * HW], t);
    t *= 3.6084391824351615e-2f;                  // 1/sqrt(768)

    float m = t;
    #pragma unroll
    for (int off = 32; off; off >>= 1) m = fmaxf(m, __shfl_xor(m, off));
    float e = __expf(t - m);
    float sum = e;
    #pragma unroll
    for (int off = 32; off; off >>= 1) sum += __shfl_xor(sum, off);
    attn_lds[n][w] = e / sum;
    __syncthreads();
    if (tid < WW) {
        float sv = 0.f;
        #pragma unroll
        for (int j = 0; j < N_; ++j) sv += attn_lds[j][tid];
        s[(size_t)b * HW + h * WW + tid] = sv;
    }

    // ---- phase 2: transpose-write x -> xT bf16 (pixel-major) ----
    int c = tid;                                   // 0..511
    const f32x4* xr = (const f32x4*)(x + ((size_t)b * C_ + c) * HW + h * WW);
    bf16* xtb = xT + ((size_t)b * HW + h * WW) * C_ + c;
    #pragma unroll 4
    for (int i = 0; i < WW / 4; ++i) {
        f32x4 v = xr[i];
        xtb[(size_t)(4*i+0) * C_] = (bf16)v[0];
        xtb[(size_t)(4*i+1) * C_] = (bf16)v[1];
        xtb[(size_t)(4*i+2) * C_] = (bf16)v[2];
        xtb[(size_t)(4*i+3) * C_] = (bf16)v[3];
    }
}

// ---------------------------------------------------------------------------
// K3: out[b,o,p] = x[b,o,p] + wo_b[o] + s[b,p] * (sum_c W2[o,c]*x[b,c,p] + b2[o])
// MFMA bf16 GEMM: A=W2 (128x64 tile), B=xT (128 pixels x 64 c), K=512.
// grid 2048, block 256 (4 waves, each 64x64 of the 128x128 tile)

__device__ __forceinline__ void gl_lds16(const void* g, void* l) {
    __builtin_amdgcn_global_load_lds(
        (const __attribute__((address_space(1))) void*)g,
        (__attribute__((address_space(3))) void*)l, 16, 0, 0);
}

__global__ __launch_bounds__(256) void k_main(const bf16* __restrict__ xT,
                                              const bf16* __restrict__ W2,
                                              const float* __restrict__ b2,
                                              const float* __restrict__ wo_b,
                                              const float* __restrict__ s,
                                              float* __restrict__ out) {
    // XCD-grouped mapping: the 4 m-tiles of one (b,pt) job land on one XCD,
    // dispatched within a 32-block window -> B-panel (128KB) L2 reuse.
    int id = blockIdx.x;
    int xcd = id & 7, chunk = id >> 3;
    int mt = chunk & 3, jrow = chunk >> 2;
    int job = jrow * 8 + xcd;                     // 0..511
    int b = job >> 5, pt = job & 31;
    int m0 = mt * 128;
    int p0 = pt * 128;
    size_t rowP = (size_t)b * HW + p0;            // xT pixel-row base

    __shared__ __align__(128) unsigned char smem[32768];
    unsigned char* Al = smem;                     // 16KB: [128 rows][64 bf16], XOR-swizzled
    unsigned char* Bl = smem + 16384;             // 16KB: same shape

    int tid = threadIdx.x;
    int wid = tid >> 6, lane = tid & 63;
    int wm = wid >> 1, wn = wid & 1;

    f32x4 acc[4][4] = {};

    for (int it = 0; it < 8; ++it) {
        int k0 = it * 64;
        __syncthreads();                          // prev-iter reads done
        #pragma unroll
        for (int q = 0; q < 4; ++q) {
            int off = (wid * 4 + q) * 1024;
            int L   = off + lane * 16;            // linear dest byte
            int row = L >> 7;                     // 0..127
            int kb  = (L & 127) ^ ((row & 7) << 4); // pre-swizzled source byte-in-row
            gl_lds16(W2 + (size_t)(m0 + row) * C_ + k0 + (kb >> 1), Al + off);
            gl_lds16(xT + (rowP + row) * C_ + k0 + (kb >> 1), Bl + off);
        }
        __syncthreads();                          // vmcnt(0) drain + barrier
        #pragma unroll
        for (int ks = 0; ks < 2; ++ks) {
            int kb0 = ks * 64 + ((lane >> 4) << 4);
            bf16x8 a[4], bb[4];
            #pragma unroll
            for (int i = 0; i < 4; ++i) {
                int row = wm * 64 + i * 16 + (lane & 15);
                a[i] = *(const bf16x8*)(Al + row * 128 + (kb0 ^ ((row & 7) << 4)));
            }
            #pragma unroll
            for (int j = 0; j < 4; ++j) {
                int row = wn * 64 + j * 16 + (lane & 15);
                bb[j] = *(const bf16x8*)(Bl + row * 128 + (kb0 ^ ((row & 7) << 4)));
            }
            #pragma unroll
            for (int i = 0; i < 4; ++i)
                #pragma unroll
                for (int j = 0; j < 4; ++j)
                    acc[i][j] = __builtin_amdgcn_mfma_f32_16x16x32_bf16(
                                    a[i], bb[j], acc[i][j], 0, 0, 0);
        }
    }

    // epilogue: out = res + wo_b + s*(acc + b2); residual from L2-hot xT (bf16)
    int r4 = (lane >> 4) << 2;
    int cl = lane & 15;
    #pragma unroll
    for (int j = 0; j < 4; ++j) {
        int p = p0 + wn * 64 + j * 16 + cl;
        float sv = s[(size_t)b * HW + p];
        const bf16* xrow = xT + ((size_t)b * HW + p) * C_;
        #pragma unroll
        for (int i = 0; i < 4; ++i) {
            int ob = m0 + wm * 64 + i * 16 + r4;
            f32x4 b2v = *(const f32x4*)(b2 + ob);
            f32x4 wbv = *(const f32x4*)(wo_b + ob);
            bf16x4 rx = *(const bf16x4*)(xrow + ob);
            #pragma unroll
            for (int r = 0; r < 4; ++r) {
                float y = acc[i][j][r] + b2v[r];
                out[((size_t)b * C_ + ob + r) * HW + p] = (float)rx[r] + wbv[r] + sv * y;
            }
        }
    }
}

// ---------------------------------------------------------------------------
extern "C" void kernel_launch(void* const* d_in, const int* in_sizes, int n_in,
                              void* d_out, int out_size, void* d_ws, size_t ws_size,
                              hipStream_t stream) {
    const float* x    = (const float*)d_in[0];
    const float* se   = (const float*)d_in[1];
    const float* wts  = (const float*)d_in[2];
    const float* wq_w = (const float*)d_in[3];
    const float* wq_b = (const float*)d_in[4];
    const float* wk_w = (const float*)d_in[5];
    // d_in[6] = wk_b: cancels in softmax (constant over w), unused
    const float* wv_w = (const float*)d_in[7];
    const float* wv_b = (const float*)d_in[8];
    const float* wo_w = (const float*)d_in[9];
    const float* wo_b = (const float*)d_in[10];
    float* out = (float*)d_out;

    // workspace layout (needs ~68MB; xT is the big piece)
    char* ws = (char*)d_ws;
    float* Q   = (float*)(ws + 0);          // 256KB
    float* Qk  = (float*)(ws + 262144);     // 256KB
    bf16*  W2  = (bf16*) (ws + 524288);     // 512KB
    float* b2  = (float*)(ws + 1048576);    // 2KB
    float* s   = (float*)(ws + 1050624);    // 256KB
    bf16*  xT  = (bf16*) (ws + 2097152);    // 64MB

    k_q     <<<dim3(128),  dim3(512), 0, stream>>>(se, wts, wq_w, wq_b, Q);
    k_qk    <<<dim3(128),  dim3(128), 0, stream>>>(Q, wk_w, Qk);
    k_w2    <<<dim3(128),  dim3(128), 0, stream>>>(wo_w, wv_w, wv_b, W2, b2);
    k_scores<<<dim3(1024), dim3(512), 0, stream>>>(x, Qk, s, xT);
    k_main  <<<dim3(2048), dim3(256), 0, stream>>>(xT, W2, b2, wo_b, s, out);
}

// Round 2
// 300.221 us; speedup vs baseline: 1.3495x; 1.3495x over previous
//
#include <hip/hip_runtime.h>
#include <hip/hip_bf16.h>

// Problem dims (fixed by reference setup)
#define B_   16
#define N_   8
#define C_   512
#define D_   768
#define HH   64
#define WW   64
#define HW   4096          // 64*64 pixels per batch

typedef __bf16 bf16;
typedef __attribute__((ext_vector_type(8))) __bf16 bf16x8;
typedef __attribute__((ext_vector_type(4))) __bf16 bf16x4;
typedef __attribute__((ext_vector_type(4))) float  f32x4;

// ---------------------------------------------------------------------------
// K1a: Q[b,n,c] = sum_d (se[b,n,d]*weights[n]) * wq_w[c,d] + wq_b[c]
// grid 128=(b,n), block 512=c
__global__ __launch_bounds__(512) void k_q(const float* __restrict__ se,
                                           const float* __restrict__ weights,
                                           const float* __restrict__ wq_w,
                                           const float* __restrict__ wq_b,
                                           float* __restrict__ Q) {
    int bn = blockIdx.x;
    int n  = bn & 7;
    float wt = weights[n];                       // uniform
    const float* we = se + (size_t)bn * D_;      // uniform base
    int c = threadIdx.x;
    const f32x4* wr = (const f32x4*)(wq_w + (size_t)c * D_);
    float acc = wq_b[c];
    #pragma unroll 4
    for (int i = 0; i < D_ / 4; ++i) {
        f32x4 w4 = wr[i];
        acc += (we[4*i+0] * wt) * w4[0];
        acc += (we[4*i+1] * wt) * w4[1];
        acc += (we[4*i+2] * wt) * w4[2];
        acc += (we[4*i+3] * wt) * w4[3];
    }
    Q[(size_t)bn * C_ + c] = acc;
}

// ---------------------------------------------------------------------------
// K1b: Qk[b,n,m] = sum_o Q[b,n,o] * wk_w[o,m]   (wk_b cancels in softmax)
// grid 128=(b,n), block 512 (thread = m).  q[o] is block-uniform -> s_load;
// wk_w[o*512+m] is lane-coalesced.  8 waves/block hides L2 latency.
__global__ __launch_bounds__(512) void k_qk(const float* __restrict__ Q,
                                            const float* __restrict__ wk_w,
                                            float* __restrict__ Qk) {
    int bn = blockIdx.x;
    const float* q = Q + (size_t)bn * C_;        // uniform base
    int m = threadIdx.x;
    float acc = 0.f;
    #pragma unroll 8
    for (int o = 0; o < C_; ++o)
        acc = fmaf(q[o], wk_w[(size_t)o * C_ + m], acc);
    Qk[(size_t)bn * C_ + m] = acc;
}

// ---------------------------------------------------------------------------
// K1c: W2[o,c] = sum_m wo_w[o,m]*wv_w[m,c]  (bf16 out);  b2[o] = wo_w[o,:]·wv_b
// grid 128 (4 o-rows each), block 512 (thread = c).  wo_w reads are
// block-uniform scalar loads; wv_w stream is lane-coalesced; 8 waves/block.
__global__ __launch_bounds__(512) void k_w2(const float* __restrict__ wo_w,
                                            const float* __restrict__ wv_w,
                                            const float* __restrict__ wv_b,
                                            bf16* __restrict__ W2,
                                            float* __restrict__ b2) {
    int o0 = blockIdx.x * 4;
    int c  = threadIdx.x;
    const float* r0 = wo_w + (size_t)o0 * C_;     // uniform rows
    float a0 = 0.f, a1 = 0.f, a2 = 0.f, a3 = 0.f;
    #pragma unroll 8
    for (int m = 0; m < C_; ++m) {
        float v = wv_w[(size_t)m * C_ + c];
        a0 = fmaf(r0[m],          v, a0);
        a1 = fmaf(r0[C_ + m],     v, a1);
        a2 = fmaf(r0[2 * C_ + m], v, a2);
        a3 = fmaf(r0[3 * C_ + m], v, a3);
    }
    W2[(size_t)(o0 + 0) * C_ + c] = (bf16)a0;
    W2[(size_t)(o0 + 1) * C_ + c] = (bf16)a1;
    W2[(size_t)(o0 + 2) * C_ + c] = (bf16)a2;
    W2[(size_t)(o0 + 3) * C_ + c] = (bf16)a3;
    if (c < 4) {                                  // b2 for this block's 4 rows
        float sb = 0.f;
        const float* rr = wo_w + (size_t)(o0 + c) * C_;
        #pragma unroll 4
        for (int m = 0; m < C_; ++m) sb = fmaf(rr[m], wv_b[m], sb);
        b2[o0 + c] = sb;
    }
}

// ---------------------------------------------------------------------------
// K2: per (b,h): scores t[n,w] = Qk[b,n,:]·x[b,:,h,w]/sqrt(768); softmax over w;
//     s[b,p] = sum_n attn.  Also writes xT[b,p,c] = bf16(x[b,c,p]) (transpose).
// grid 1024=(b,h), block 512 (wave = n, lane = w)
__global__ __launch_bounds__(512) void k_scores(const float* __restrict__ x,
                                                const float* __restrict__ Qk,
                                                float* __restrict__ s,
                                                bf16* __restrict__ xT) {
    int blk = blockIdx.x;
    int b = blk >> 6, h = blk & 63;
    int tid = threadIdx.x;
    int n = tid >> 6, w = tid & 63;
    __shared__ float attn_lds[N_][WW];

    // ---- phase 1: scores + softmax ----
    int n_u = __builtin_amdgcn_readfirstlane(n);  // wave-uniform
    const float* qrow = Qk + ((size_t)(b * N_ + n_u)) * C_;
    const float* xcol = x + (size_t)b * C_ * HW + h * WW + w;
    float t = 0.f;
    #pragma unroll 8
    for (int c = 0; c < C_; ++c)
        t = fmaf(qrow[c], xcol[(size_t)c * HW], t);
    t *= 3.6084391824351615e-2f;                  // 1/sqrt(768)

    float m = t;
    #pragma unroll
    for (int off = 32; off; off >>= 1) m = fmaxf(m, __shfl_xor(m, off));
    float e = __expf(t - m);
    float sum = e;
    #pragma unroll
    for (int off = 32; off; off >>= 1) sum += __shfl_xor(sum, off);
    attn_lds[n][w] = e / sum;
    __syncthreads();
    if (tid < WW) {
        float sv = 0.f;
        #pragma unroll
        for (int j = 0; j < N_; ++j) sv += attn_lds[j][tid];
        s[(size_t)b * HW + h * WW + tid] = sv;
    }

    // ---- phase 2: transpose-write x -> xT bf16 (pixel-major) ----
    int c = tid;                                   // 0..511
    const f32x4* xr = (const f32x4*)(x + ((size_t)b * C_ + c) * HW + h * WW);
    bf16* xtb = xT + ((size_t)b * HW + h * WW) * C_ + c;
    #pragma unroll 4
    for (int i = 0; i < WW / 4; ++i) {
        f32x4 v = xr[i];
        xtb[(size_t)(4*i+0) * C_] = (bf16)v[0];
        xtb[(size_t)(4*i+1) * C_] = (bf16)v[1];
        xtb[(size_t)(4*i+2) * C_] = (bf16)v[2];
        xtb[(size_t)(4*i+3) * C_] = (bf16)v[3];
    }
}

// ---------------------------------------------------------------------------
// K3: out[b,o,p] = x[b,o,p] + wo_b[o] + s[b,p] * (sum_c W2[o,c]*x[b,c,p] + b2[o])
// MFMA bf16 GEMM: A=W2 (128x64 tile), B=xT (128 pixels x 64 c), K=512.
// grid 2048, block 256 (4 waves, each 64x64 of the 128x128 tile)

__device__ __forceinline__ void gl_lds16(const void* g, void* l) {
    __builtin_amdgcn_global_load_lds(
        (const __attribute__((address_space(1))) void*)g,
        (__attribute__((address_space(3))) void*)l, 16, 0, 0);
}

__global__ __launch_bounds__(256) void k_main(const bf16* __restrict__ xT,
                                              const bf16* __restrict__ W2,
                                              const float* __restrict__ b2,
                                              const float* __restrict__ wo_b,
                                              const float* __restrict__ s,
                                              float* __restrict__ out) {
    // XCD-grouped mapping: the 4 m-tiles of one (b,pt) job land on one XCD,
    // dispatched within a 32-block window -> B-panel (128KB) L2 reuse.
    int id = blockIdx.x;
    int xcd = id & 7, chunk = id >> 3;
    int mt = chunk & 3, jrow = chunk >> 2;
    int job = jrow * 8 + xcd;                     // 0..511
    int b = job >> 5, pt = job & 31;
    int m0 = mt * 128;
    int p0 = pt * 128;
    size_t rowP = (size_t)b * HW + p0;            // xT pixel-row base

    __shared__ __align__(128) unsigned char smem[32768];
    unsigned char* Al = smem;                     // 16KB: [128 rows][64 bf16], XOR-swizzled
    unsigned char* Bl = smem + 16384;             // 16KB: same shape

    int tid = threadIdx.x;
    int wid = tid >> 6, lane = tid & 63;
    int wm = wid >> 1, wn = wid & 1;

    f32x4 acc[4][4] = {};

    for (int it = 0; it < 8; ++it) {
        int k0 = it * 64;
        __syncthreads();                          // prev-iter reads done
        #pragma unroll
        for (int q = 0; q < 4; ++q) {
            int off = (wid * 4 + q) * 1024;
            int L   = off + lane * 16;            // linear dest byte
            int row = L >> 7;                     // 0..127
            int kb  = (L & 127) ^ ((row & 7) << 4); // pre-swizzled source byte-in-row
            gl_lds16(W2 + (size_t)(m0 + row) * C_ + k0 + (kb >> 1), Al + off);
            gl_lds16(xT + (rowP + row) * C_ + k0 + (kb >> 1), Bl + off);
        }
        __syncthreads();                          // vmcnt(0) drain + barrier
        #pragma unroll
        for (int ks = 0; ks < 2; ++ks) {
            int kb0 = ks * 64 + ((lane >> 4) << 4);
            bf16x8 a[4], bb[4];
            #pragma unroll
            for (int i = 0; i < 4; ++i) {
                int row = wm * 64 + i * 16 + (lane & 15);
                a[i] = *(const bf16x8*)(Al + row * 128 + (kb0 ^ ((row & 7) << 4)));
            }
            #pragma unroll
            for (int j = 0; j < 4; ++j) {
                int row = wn * 64 + j * 16 + (lane & 15);
                bb[j] = *(const bf16x8*)(Bl + row * 128 + (kb0 ^ ((row & 7) << 4)));
            }
            #pragma unroll
            for (int i = 0; i < 4; ++i)
                #pragma unroll
                for (int j = 0; j < 4; ++j)
                    acc[i][j] = __builtin_amdgcn_mfma_f32_16x16x32_bf16(
                                    a[i], bb[j], acc[i][j], 0, 0, 0);
        }
    }

    // epilogue: out = res + wo_b + s*(acc + b2); residual from L2-hot xT (bf16)
    int r4 = (lane >> 4) << 2;
    int cl = lane & 15;
    #pragma unroll
    for (int j = 0; j < 4; ++j) {
        int p = p0 + wn * 64 + j * 16 + cl;
        float sv = s[(size_t)b * HW + p];
        const bf16* xrow = xT + ((size_t)b * HW + p) * C_;
        #pragma unroll
        for (int i = 0; i < 4; ++i) {
            int ob = m0 + wm * 64 + i * 16 + r4;
            f32x4 b2v = *(const f32x4*)(b2 + ob);
            f32x4 wbv = *(const f32x4*)(wo_b + ob);
            bf16x4 rx = *(const bf16x4*)(xrow + ob);
            #pragma unroll
            for (int r = 0; r < 4; ++r) {
                float y = acc[i][j][r] + b2v[r];
                out[((size_t)b * C_ + ob + r) * HW + p] = (float)rx[r] + wbv[r] + sv * y;
            }
        }
    }
}

// ---------------------------------------------------------------------------
extern "C" void kernel_launch(void* const* d_in, const int* in_sizes, int n_in,
                              void* d_out, int out_size, void* d_ws, size_t ws_size,
                              hipStream_t stream) {
    const float* x    = (const float*)d_in[0];
    const float* se   = (const float*)d_in[1];
    const float* wts  = (const float*)d_in[2];
    const float* wq_w = (const float*)d_in[3];
    const float* wq_b = (const float*)d_in[4];
    const float* wk_w = (const float*)d_in[5];
    // d_in[6] = wk_b: cancels in softmax (constant over w), unused
    const float* wv_w = (const float*)d_in[7];
    const float* wv_b = (const float*)d_in[8];
    const float* wo_w = (const float*)d_in[9];
    const float* wo_b = (const float*)d_in[10];
    float* out = (float*)d_out;

    // workspace layout (needs ~68MB; xT is the big piece)
    char* ws = (char*)d_ws;
    float* Q   = (float*)(ws + 0);          // 256KB
    float* Qk  = (float*)(ws + 262144);     // 256KB
    bf16*  W2  = (bf16*) (ws + 524288);     // 512KB
    float* b2  = (float*)(ws + 1048576);    // 2KB
    float* s   = (float*)(ws + 1050624);    // 256KB
    bf16*  xT  = (bf16*) (ws + 2097152);    // 64MB

    k_q     <<<dim3(128),  dim3(512), 0, stream>>>(se, wts, wq_w, wq_b, Q);
    k_qk    <<<dim3(128),  dim3(512), 0, stream>>>(Q, wk_w, Qk);
    k_w2    <<<dim3(128),  dim3(512), 0, stream>>>(wo_w, wv_w, wv_b, W2, b2);
    k_scores<<<dim3(1024), dim3(512), 0, stream>>>(x, Qk, s, xT);
    k_main  <<<dim3(2048), dim3(256), 0, stream>>>(xT, W2, b2, wo_b, s, out);
}